// Round 1
// baseline (209.569 us; speedup 1.0000x reference)
//
#include <hip/hip_runtime.h>

// NURBS surface eval, two-stage separable form.
//   Stage 1 (per block = one batch b x 8 U-rows): contract over u into LDS:
//     rows[u][n][0:4] = sum_l Nu[U,l] * ctrl[b, iu[U,l], n, 0:4]   (n = 0..63)
//   Stage 2: each thread owns a consecutive V-PAIR (V = 2t, 2t+1), loops u=0..7:
//     surf = sum_r Nv[V,r] * rows[u][iv[V,r]];  out = surf.xyz / surf.w
//   The pair's 24 B output is written as 3 x float2 stores (8B-aligned since
//   V0 is even -> byte offset multiple of 24), replacing 6 scalar dword
//   stores + per-point 64-bit address math. Per-wave V-range stays 128 ->
//   ~15 distinct rows[] entries per ds_read_b128 -> <=2-way bank aliasing
//   (free per m136).

#define OUTDIM 512
#define CTRL_N 64
#define TU 8

__global__ __launch_bounds__(256) void surf_eval_kernel(
    const float* __restrict__ ctrl,   // [B,64,64,4]
    const float* __restrict__ Nu,     // [512,4]
    const float* __restrict__ Nv,     // [512,4]
    const int*   __restrict__ iu,     // [512,4]
    const int*   __restrict__ iv,     // [512,4]
    float*       __restrict__ out)    // [B,512,512,3]
{
    __shared__ float4 rows[TU * CTRL_N];   // 8 KB

    const int blk = blockIdx.x;
    const int b  = blk >> 6;               // 0..63
    const int U0 = (blk & 63) * TU;        // 0,8,...,504
    const int t  = threadIdx.x;

    // ---------- stage 1: u-contraction into LDS (unchanged) ----------
    {
        const int u  = t >> 5;             // 0..7
        const int n0 = t & 31;             // 0..31 (+32 for second point)
        const int U  = U0 + u;
        const float4 nu  = *(const float4*)(Nu + U * 4);
        const int4   iu4 = *(const int4*)(iu + U * 4);
        const float* cb = ctrl + (size_t)b * (64 * 64 * 4);
        const float* r0 = cb + (size_t)iu4.x * (CTRL_N * 4);
        const float* r1 = cb + (size_t)iu4.y * (CTRL_N * 4);
        const float* r2 = cb + (size_t)iu4.z * (CTRL_N * 4);
        const float* r3 = cb + (size_t)iu4.w * (CTRL_N * 4);

#pragma unroll
        for (int k = 0; k < 2; ++k) {
            const int n = n0 + 32 * k;
            const float4 p0 = *(const float4*)(r0 + n * 4);
            const float4 p1 = *(const float4*)(r1 + n * 4);
            const float4 p2 = *(const float4*)(r2 + n * 4);
            const float4 p3 = *(const float4*)(r3 + n * 4);
            float4 acc;
            acc.x = nu.x * p0.x + nu.y * p1.x + nu.z * p2.x + nu.w * p3.x;
            acc.y = nu.x * p0.y + nu.y * p1.y + nu.z * p2.y + nu.w * p3.y;
            acc.z = nu.x * p0.z + nu.y * p1.z + nu.z * p2.z + nu.w * p3.z;
            acc.w = nu.x * p0.w + nu.y * p1.w + nu.z * p2.w + nu.w * p3.w;
            rows[u * CTRL_N + n] = acc;
        }
    }
    __syncthreads();

    // ---------- stage 2: v-contraction from LDS ----------
    // Thread t handles the consecutive pair V = 2t and V = 2t+1.
    const int v0 = t << 1;
    const float4 nvA = *(const float4*)(Nv + v0 * 4);
    const int4   ivA = *(const int4*)(iv + v0 * 4);
    const float4 nvB = *(const float4*)(Nv + v0 * 4 + 4);
    const int4   ivB = *(const int4*)(iv + v0 * 4 + 4);

    // 32-bit offsets are safe: out is 201 MB (< 4 GiB).
    float* ob = out + (((size_t)b * OUTDIM + U0) * OUTDIM + v0) * 3;

#pragma unroll
    for (int u = 0; u < TU; ++u) {
        const float4* ru = rows + u * CTRL_N;

        const float4 a0 = ru[ivA.x];
        const float4 a1 = ru[ivA.y];
        const float4 a2 = ru[ivA.z];
        const float4 a3 = ru[ivA.w];
        const float4 b0 = ru[ivB.x];
        const float4 b1 = ru[ivB.y];
        const float4 b2 = ru[ivB.z];
        const float4 b3 = ru[ivB.w];

        float sxA = nvA.x * a0.x + nvA.y * a1.x + nvA.z * a2.x + nvA.w * a3.x;
        float syA = nvA.x * a0.y + nvA.y * a1.y + nvA.z * a2.y + nvA.w * a3.y;
        float szA = nvA.x * a0.z + nvA.y * a1.z + nvA.z * a2.z + nvA.w * a3.z;
        float swA = nvA.x * a0.w + nvA.y * a1.w + nvA.z * a2.w + nvA.w * a3.w;

        float sxB = nvB.x * b0.x + nvB.y * b1.x + nvB.z * b2.x + nvB.w * b3.x;
        float syB = nvB.x * b0.y + nvB.y * b1.y + nvB.z * b2.y + nvB.w * b3.y;
        float szB = nvB.x * b0.z + nvB.y * b1.z + nvB.z * b2.z + nvB.w * b3.z;
        float swB = nvB.x * b0.w + nvB.y * b1.w + nvB.z * b2.w + nvB.w * b3.w;

        const float invA = __builtin_amdgcn_rcpf(swA);
        const float invB = __builtin_amdgcn_rcpf(swB);

        float* po = ob + u * (OUTDIM * 3);
        // 24 B for the pair as 3 x float2 (byte offset is a multiple of 24
        // -> 8-byte aligned everywhere).
        *(float2*)(po + 0) = make_float2(sxA * invA, syA * invA);
        *(float2*)(po + 2) = make_float2(szA * invA, sxB * invB);
        *(float2*)(po + 4) = make_float2(syB * invB, szB * invB);
    }
}

extern "C" void kernel_launch(void* const* d_in, const int* in_sizes, int n_in,
                              void* d_out, int out_size, void* d_ws, size_t ws_size,
                              hipStream_t stream) {
    const float* ctrl = (const float*)d_in[0];
    const float* Nu   = (const float*)d_in[1];
    const float* Nv   = (const float*)d_in[2];
    const int*   iu   = (const int*)d_in[3];
    const int*   iv   = (const int*)d_in[4];
    float* out = (float*)d_out;

    // grid: 64 batches x 64 U-tiles (of 8 rows) = 4096 blocks of 256 threads
    const int nblocks = 64 * (OUTDIM / TU);
    surf_eval_kernel<<<nblocks, 256, 0, stream>>>(ctrl, Nu, Nv, iu, iv, out);
}

// Round 2
// 205.973 us; speedup vs baseline: 1.0175x; 1.0175x over previous
//
#include <hip/hip_runtime.h>

// NURBS surface eval, two-stage separable form.
//   Stage 1 (per block = one batch b x 8 U-rows): contract over u into LDS:
//     rows[u][n][0:4] = sum_l Nu[U,l] * ctrl[b, iu[U,l], n, 0:4]   (n = 0..63)
//   Stage 2: thread t computes the V-pair (2t, 2t+1) for each u.
//     Gathers use the consecutive-base trick: iv[2t+1].x - iv[2t].x in {0,1}
//     (knot intervals span ~8.5 samples), so FIVE consecutive float4 reads
//     from base iv[2t].x cover both points; point B uses a 5-wide weight
//     vector selected once per thread.
//   Output path: 12 B/point direct stores cover only 1/3 of each 64-B line
//     per instruction (3x TCC write transactions -> ~2.2 TB/s effective,
//     the round-0/1 bottleneck). Fix: stage the 6144-B u-row in LDS
//     (double-buffered), read back linearly, store as lane-contiguous
//     dwordx4 -> full-line write requests. One __syncthreads per u;
//     next-u compute overlaps current-u readback.

#define OUTDIM 512
#define CTRL_N 64
#define TU 8

__global__ __launch_bounds__(256) void surf_eval_kernel(
    const float* __restrict__ ctrl,   // [B,64,64,4]
    const float* __restrict__ Nu,     // [512,4]
    const float* __restrict__ Nv,     // [512,4]
    const int*   __restrict__ iu,     // [512,4]
    const int*   __restrict__ iv,     // [512,4]
    float*       __restrict__ out)    // [B,512,512,3]
{
    __shared__ float4 rows[TU * CTRL_N];                     // 8 KB
    __shared__ __align__(16) float stg[2][OUTDIM * 3];       // 2 x 6 KB

    const int blk = blockIdx.x;
    const int b  = blk >> 6;               // 0..63
    const int U0 = (blk & 63) * TU;        // 0,8,...,504
    const int t  = threadIdx.x;

    // ---------- stage 1: u-contraction into LDS ----------
    {
        const int u  = t >> 5;             // 0..7
        const int n0 = t & 31;             // 0..31 (+32 for second point)
        const int U  = U0 + u;
        const float4 nu  = *(const float4*)(Nu + U * 4);
        const int4   iu4 = *(const int4*)(iu + U * 4);
        const float* cb = ctrl + (size_t)b * (64 * 64 * 4);
        const float* r0 = cb + (size_t)iu4.x * (CTRL_N * 4);
        const float* r1 = cb + (size_t)iu4.y * (CTRL_N * 4);
        const float* r2 = cb + (size_t)iu4.z * (CTRL_N * 4);
        const float* r3 = cb + (size_t)iu4.w * (CTRL_N * 4);

#pragma unroll
        for (int k = 0; k < 2; ++k) {
            const int n = n0 + 32 * k;
            const float4 p0 = *(const float4*)(r0 + n * 4);
            const float4 p1 = *(const float4*)(r1 + n * 4);
            const float4 p2 = *(const float4*)(r2 + n * 4);
            const float4 p3 = *(const float4*)(r3 + n * 4);
            float4 acc;
            acc.x = nu.x * p0.x + nu.y * p1.x + nu.z * p2.x + nu.w * p3.x;
            acc.y = nu.x * p0.y + nu.y * p1.y + nu.z * p2.y + nu.w * p3.y;
            acc.z = nu.x * p0.z + nu.y * p1.z + nu.z * p2.z + nu.w * p3.z;
            acc.w = nu.x * p0.w + nu.y * p1.w + nu.z * p2.w + nu.w * p3.w;
            rows[u * CTRL_N + n] = acc;
        }
    }
    __syncthreads();

    // ---------- stage 2 setup ----------
    const int v0 = t << 1;
    const float4 nvA = *(const float4*)(Nv + v0 * 4);
    const float4 nvB = *(const float4*)(Nv + v0 * 4 + 4);
    const int    iA  = iv[v0 * 4];                 // iv[2t].x
    const int    dB  = iv[v0 * 4 + 4] - iA;        // iv[2t+1].x - iv[2t].x, 0 or 1

    // 5-wide weights for point B over q[0..4] (selected once; dB is loop-invariant)
    const float wB0 = dB ? 0.0f  : nvB.x;
    const float wB1 = dB ? nvB.x : nvB.y;
    const float wB2 = dB ? nvB.y : nvB.z;
    const float wB3 = dB ? nvB.z : nvB.w;
    const float wB4 = dB ? nvB.w : 0.0f;

    float* orow = out + ((size_t)b * OUTDIM + U0) * (OUTDIM * 3);

    auto compute_and_stage = [&](int u) {
        const float4* ru = rows + u * CTRL_N;
        const float4 q0 = ru[iA + 0];
        const float4 q1 = ru[iA + 1];
        const float4 q2 = ru[iA + 2];
        const float4 q3 = ru[iA + 3];
        const float4 q4 = ru[iA + 4];

        float sxA = nvA.x * q0.x + nvA.y * q1.x + nvA.z * q2.x + nvA.w * q3.x;
        float syA = nvA.x * q0.y + nvA.y * q1.y + nvA.z * q2.y + nvA.w * q3.y;
        float szA = nvA.x * q0.z + nvA.y * q1.z + nvA.z * q2.z + nvA.w * q3.z;
        float swA = nvA.x * q0.w + nvA.y * q1.w + nvA.z * q2.w + nvA.w * q3.w;

        float sxB = wB0 * q0.x + wB1 * q1.x + wB2 * q2.x + wB3 * q3.x + wB4 * q4.x;
        float syB = wB0 * q0.y + wB1 * q1.y + wB2 * q2.y + wB3 * q3.y + wB4 * q4.y;
        float szB = wB0 * q0.z + wB1 * q1.z + wB2 * q2.z + wB3 * q3.z + wB4 * q4.z;
        float swB = wB0 * q0.w + wB1 * q1.w + wB2 * q2.w + wB3 * q3.w + wB4 * q4.w;

        const float invA = __builtin_amdgcn_rcpf(swA);
        const float invB = __builtin_amdgcn_rcpf(swB);

        // 24 B to staging at float offset 6t (8-byte aligned: 24t)
        float2* sp = (float2*)&stg[u & 1][6 * t];
        sp[0] = make_float2(sxA * invA, syA * invA);
        sp[1] = make_float2(szA * invA, sxB * invB);
        sp[2] = make_float2(syB * invB, szB * invB);
    };

    compute_and_stage(0);

#pragma unroll
    for (int u = 0; u < TU; ++u) {
        __syncthreads();
        // overlap: fill the OTHER staging buffer while this one drains
        if (u + 1 < TU) compute_and_stage(u + 1);

        // linear readback -> fully coalesced dwordx4 stores (full-line requests)
        const float4* sb = (const float4*)stg[u & 1];
        float* og = orow + u * (OUTDIM * 3);           // 6144 B, 16B-aligned
        *(float4*)(og + 4 * t) = sb[t];                // chunks 0..255
        if (t < 128)
            *(float4*)(og + 4 * (256 + t)) = sb[256 + t];  // chunks 256..383
    }
}

extern "C" void kernel_launch(void* const* d_in, const int* in_sizes, int n_in,
                              void* d_out, int out_size, void* d_ws, size_t ws_size,
                              hipStream_t stream) {
    const float* ctrl = (const float*)d_in[0];
    const float* Nu   = (const float*)d_in[1];
    const float* Nv   = (const float*)d_in[2];
    const int*   iu   = (const int*)d_in[3];
    const int*   iv   = (const int*)d_in[4];
    float* out = (float*)d_out;

    // grid: 64 batches x 64 U-tiles (of 8 rows) = 4096 blocks of 256 threads
    const int nblocks = 64 * (OUTDIM / TU);
    surf_eval_kernel<<<nblocks, 256, 0, stream>>>(ctrl, Nu, Nv, iu, iv, out);
}